// Round 1
// baseline (167.304 us; speedup 1.0000x reference)
//
#include <hip/hip_runtime.h>

#define JCHUNK 250
#define IR 4
#define BLOCK 256

// ws layout (float4 units): A_mesh0[F], A_mesh1[F], B_mesh0[F], B_mesh1[F]
// A = (cx, cy, cz, |C|^2), B = (nx, ny, nz, L)

__global__ void geom_kernel(const float* __restrict__ pred,
                            const float* __restrict__ targ,
                            const int* __restrict__ pf,
                            const int* __restrict__ tf,
                            float4* __restrict__ ws4, int F)
{
    int id = blockIdx.x * blockDim.x + threadIdx.x;
    if (id >= 2 * F) return;
    int m = id / F;
    int f = id - m * F;
    const float* Vv = m ? targ : pred;
    const int* Fc = m ? tf : pf;
    int i0 = Fc[3 * f + 0];
    int i1 = Fc[3 * f + 1];
    int i2 = Fc[3 * f + 2];
    float ax = Vv[3 * i0 + 0], ay = Vv[3 * i0 + 1], az = Vv[3 * i0 + 2];
    float bx = Vv[3 * i1 + 0], by = Vv[3 * i1 + 1], bz = Vv[3 * i1 + 2];
    float cx = Vv[3 * i2 + 0], cy = Vv[3 * i2 + 1], cz = Vv[3 * i2 + 2];

    const float third = 1.0f / 3.0f;
    float Cx = (ax + bx + cx) * third;
    float Cy = (ay + by + cy) * third;
    float Cz = (az + bz + cz) * third;

    float e1x = bx - ax, e1y = by - ay, e1z = bz - az;
    float e2x = cx - ax, e2y = cy - ay, e2z = cz - az;
    float Nx = 0.5f * (e1y * e2z - e1z * e2y);
    float Ny = 0.5f * (e1z * e2x - e1x * e2z);
    float Nz = 0.5f * (e1x * e2y - e1y * e2x);
    float L = sqrtf(Nx * Nx + Ny * Ny + Nz * Nz + 1e-12f);
    float inv = 1.0f / L;

    ws4[m * F + f] = make_float4(Cx, Cy, Cz, Cx * Cx + Cy * Cy + Cz * Cz);
    ws4[2 * F + m * F + f] = make_float4(Nx * inv, Ny * inv, Nz * inv, L);
}

__launch_bounds__(BLOCK)
__global__ void pair_kernel(const float4* __restrict__ ws4,
                            float* __restrict__ out, int F)
{
    // exp(-d2/s^2) = exp2(d2 * K), K = -1/(s^2 * ln2)
    const float K1 = (float)(-1.0 / (0.08 * 0.08 * 0.69314718055994530942));
    const float K2 = (float)(-1.0 / (0.02 * 0.02 * 0.69314718055994530942));
    const float W2 = 0.0625f; // (0.02/0.08)^2

    int nJC = (F + JCHUNK - 1) / JCHUNK;
    int iPerBlk = BLOCK * IR;
    int nIB = (F + iPerBlk - 1) / iPerBlk;
    int perTerm = nIB * nJC;

    int t = blockIdx.x / perTerm;
    int r = blockIdx.x - t * perTerm;
    int ib = r / nJC;
    int jc = r - ib * nJC;

    int X = (t == 1) ? 1 : 0;
    int Y = (t == 0) ? 0 : 1;
    float coeff = (t == 2) ? -2.0f : 1.0f;

    const float4* __restrict__ A_x = ws4 + X * F;
    const float4* __restrict__ B_x = ws4 + 2 * F + X * F;
    const float4* __restrict__ A_y = ws4 + Y * F;
    const float4* __restrict__ B_y = ws4 + 2 * F + Y * F;

    __shared__ float4 sA[JCHUNK];
    __shared__ float4 sB[JCHUNK];

    int tid = threadIdx.x;
    int j0 = jc * JCHUNK;
    int jn = (F - j0 < JCHUNK) ? (F - j0) : JCHUNK;
    for (int s = tid; s < jn; s += BLOCK) {
        sA[s] = A_y[j0 + s];
        sB[s] = B_y[j0 + s];
    }
    __syncthreads();

    float cxi[IR], cyi[IR], czi[IR], c2i[IR];
    float nxi[IR], nyi[IR], nzi[IR], Li[IR], acc[IR];
    int ibase = ib * iPerBlk + tid;
#pragma unroll
    for (int k = 0; k < IR; k++) {
        int i = ibase + k * BLOCK;
        float4 a = make_float4(0.f, 0.f, 0.f, 0.f);
        float4 b = make_float4(0.f, 0.f, 0.f, 0.f);
        if (i < F) { a = A_x[i]; b = B_x[i]; }
        cxi[k] = a.x; cyi[k] = a.y; czi[k] = a.z; c2i[k] = a.w;
        nxi[k] = b.x; nyi[k] = b.y; nzi[k] = b.z; Li[k] = b.w;
        acc[k] = 0.0f;
    }

    for (int j = 0; j < jn; j++) {
        float4 a = sA[j];
        float4 b = sB[j];
#pragma unroll
        for (int k = 0; k < IR; k++) {
            float dot = cxi[k] * a.x + cyi[k] * a.y + czi[k] * a.z;
            float d2 = c2i[k] + a.w - 2.0f * dot;
            float nd = nxi[k] * b.x + nyi[k] * b.y + nzi[k] * b.z;
            float p = nd * nd * b.w;
            float e = __builtin_amdgcn_exp2f(d2 * K1)
                    + W2 * __builtin_amdgcn_exp2f(d2 * K2);
            acc[k] = fmaf(p, e, acc[k]);
        }
    }

    float ps = 0.0f;
#pragma unroll
    for (int k = 0; k < IR; k++) ps += Li[k] * acc[k];
    ps *= coeff;

    // wave (64-lane) reduction
    for (int off = 32; off > 0; off >>= 1) ps += __shfl_down(ps, off, 64);

    __shared__ float wsum[BLOCK / 64];
    int wid = tid >> 6;
    int lane = tid & 63;
    if (lane == 0) wsum[wid] = ps;
    __syncthreads();
    if (tid == 0) {
        float bs = 0.0f;
        for (int w = 0; w < BLOCK / 64; w++) bs += wsum[w];
        atomicAdd(out, bs);
    }
}

extern "C" void kernel_launch(void* const* d_in, const int* in_sizes, int n_in,
                              void* d_out, int out_size, void* d_ws, size_t ws_size,
                              hipStream_t stream) {
    const float* pred = (const float*)d_in[0];
    const float* targ = (const float*)d_in[1];
    const int* pf = (const int*)d_in[2];
    const int* tf = (const int*)d_in[3];
    float* out = (float*)d_out;
    float4* ws4 = (float4*)d_ws;

    int F = in_sizes[2] / 3; // B == 1

    hipMemsetAsync(out, 0, sizeof(float), stream);

    int gthreads = 2 * F;
    geom_kernel<<<(gthreads + BLOCK - 1) / BLOCK, BLOCK, 0, stream>>>(
        pred, targ, pf, tf, ws4, F);

    int nJC = (F + JCHUNK - 1) / JCHUNK;
    int nIB = (F + BLOCK * IR - 1) / (BLOCK * IR);
    int blocks = 3 * nIB * nJC;
    pair_kernel<<<blocks, BLOCK, 0, stream>>>(ws4, out, F);
}

// Round 2
// 126.513 us; speedup vs baseline: 1.3224x; 1.3224x over previous
//
#include <hip/hip_runtime.h>

#define BLOCK 256
#define IR 4
#define JCHUNK 128
// derived: iPerBlk = BLOCK*IR = 1024, q = iPerBlk/JCHUNK = 8

// exp(-d2/s^2) = exp2(d2*K), K = -1/(s^2*ln2);  K2 = 16*K1 exactly
#define LN2 0.69314718055994530942
#define K1F ((float)(-1.0/(0.08*0.08*LN2)))
#define W2F 0.0625f  // (0.02/0.08)^2

// ws layout (float4): A_mesh0[F], A_mesh1[F], B_mesh0[F], B_mesh1[F]
// A = (g*Cx, g*Cy, g*Cz, K1*|C|^2)   with g = sqrt(-2*K1)
// B = (Mx, My, Mz, unused)           with M = N/sqrt(L)  (area folded in)

__global__ void geom_kernel(const float* __restrict__ vpred,
                            const float* __restrict__ vtarg,
                            const int* __restrict__ pf,
                            const int* __restrict__ tf,
                            float4* __restrict__ ws4,
                            float* __restrict__ out, int F)
{
    int id = blockIdx.x * blockDim.x + threadIdx.x;
    float diag = 0.0f;
    if (id < 2 * F) {
        int m = id / F;
        int f = id - m * F;
        const float* Vv = m ? vtarg : vpred;
        const int* Fc = m ? tf : pf;
        int i0 = Fc[3 * f + 0];
        int i1 = Fc[3 * f + 1];
        int i2 = Fc[3 * f + 2];
        float ax = Vv[3 * i0 + 0], ay = Vv[3 * i0 + 1], az = Vv[3 * i0 + 2];
        float bx = Vv[3 * i1 + 0], by = Vv[3 * i1 + 1], bz = Vv[3 * i1 + 2];
        float cx = Vv[3 * i2 + 0], cy = Vv[3 * i2 + 1], cz = Vv[3 * i2 + 2];

        const float third = 1.0f / 3.0f;
        float Cx = (ax + bx + cx) * third;
        float Cy = (ay + by + cy) * third;
        float Cz = (az + bz + cz) * third;

        float e1x = bx - ax, e1y = by - ay, e1z = bz - az;
        float e2x = cx - ax, e2y = cy - ay, e2z = cz - az;
        float Nx = 0.5f * (e1y * e2z - e1z * e2y);
        float Ny = 0.5f * (e1z * e2x - e1x * e2z);
        float Nz = 0.5f * (e1x * e2y - e1y * e2x);
        float nn = Nx * Nx + Ny * Ny + Nz * Nz;
        float L = sqrtf(nn + 1e-12f);
        float invSL = 1.0f / sqrtf(L);

        const float g = sqrtf(-2.0f * K1F);
        float c2 = Cx * Cx + Cy * Cy + Cz * Cz;
        ws4[m * F + f] = make_float4(g * Cx, g * Cy, g * Cz, K1F * c2);
        ws4[2 * F + m * F + f] = make_float4(Nx * invSL, Ny * invSL, Nz * invSL, 0.0f);

        // diagonal contribution of the symmetric terms: (1+W2)*(N.N/L)^2
        float d = nn / L;
        diag = (1.0f + W2F) * d * d;
    }
    // wave reduce + one atomic per wave
    for (int off = 32; off > 0; off >>= 1) diag += __shfl_down(diag, off, 64);
    if ((threadIdx.x & 63) == 0 && diag != 0.0f) atomicAdd(out, diag);
}

#define JLOOP(PRED)                                                        \
    _Pragma("unroll 2")                                                    \
    for (int j = 0; j < jn; ++j) {                                         \
        float4 a = sJ[2 * j];                                              \
        float4 b = sJ[2 * j + 1];                                          \
        _Pragma("unroll")                                                  \
        for (int k = 0; k < IR; ++k) {                                     \
            float tt = s1i[k] + a.w;                                       \
            tt = fmaf(pxi[k], a.x, tt);                                    \
            tt = fmaf(pyi[k], a.y, tt);                                    \
            tt = fmaf(pzi[k], a.z, tt);                                    \
            float nd = mxi[k] * b.x;                                       \
            nd = fmaf(myi[k], b.y, nd);                                    \
            nd = fmaf(mzi[k], b.z, nd);                                    \
            float p = nd * nd;                                             \
            if (PRED) p = (j0 + j < ibase + k * BLOCK) ? p : 0.0f;         \
            float e1 = __builtin_amdgcn_exp2f(tt);                         \
            float e2 = __builtin_amdgcn_exp2f(tt * 16.0f);                 \
            accA[k] = fmaf(p, e1, accA[k]);                                \
            accB[k] = fmaf(p, e2, accB[k]);                                \
        }                                                                  \
    }

__launch_bounds__(BLOCK)
__global__ void pair_kernel(const float4* __restrict__ ws4,
                            float* __restrict__ out, int F,
                            int nJC, int nSym)
{
    const int q = (BLOCK * IR) / JCHUNK;
    const int iPerBlk = BLOCK * IR;

    int bid = blockIdx.x;
    int t, ib, jc;
    float coeff;
    bool predFlag = false;

    if (bid < 2 * nSym) {
        t = (bid < nSym) ? 0 : 1;
        int r = bid - t * nSym;
        int ibf = 0, off = 0;
        for (;;) {
            int c = (ibf + 1) * q;
            if (c > nJC) c = nJC;
            if (r < off + c) break;
            off += c;
            ibf++;
        }
        ib = ibf;
        jc = r - off;
        coeff = 2.0f;
        predFlag = (jc >= ib * q);  // diagonal-crossing chunk
    } else {
        int r = bid - 2 * nSym;
        t = 2;
        ib = r / nJC;
        jc = r - ib * nJC;
        coeff = -2.0f;
    }

    int X = (t == 1) ? 1 : 0;
    int Y = (t == 0) ? 0 : 1;

    const float4* __restrict__ A_x = ws4 + X * F;
    const float4* __restrict__ B_x = ws4 + 2 * F + X * F;
    const float4* __restrict__ A_y = ws4 + Y * F;
    const float4* __restrict__ B_y = ws4 + 2 * F + Y * F;

    __shared__ float4 sJ[2 * JCHUNK];

    int tid = threadIdx.x;
    int j0 = jc * JCHUNK;
    int jn = (F - j0 < JCHUNK) ? (F - j0) : JCHUNK;
    for (int s = tid; s < jn; s += BLOCK) {
        sJ[2 * s] = A_y[j0 + s];
        sJ[2 * s + 1] = B_y[j0 + s];
    }
    __syncthreads();

    float pxi[IR], pyi[IR], pzi[IR], s1i[IR];
    float mxi[IR], myi[IR], mzi[IR];
    float accA[IR], accB[IR];
    int ibase = ib * iPerBlk + tid;
#pragma unroll
    for (int k = 0; k < IR; k++) {
        int i = ibase + k * BLOCK;
        float4 a = make_float4(0.f, 0.f, 0.f, 0.f);
        float4 b = make_float4(0.f, 0.f, 0.f, 0.f);
        if (i < F) { a = A_x[i]; b = B_x[i]; }
        pxi[k] = a.x; pyi[k] = a.y; pzi[k] = a.z; s1i[k] = a.w;
        mxi[k] = b.x; myi[k] = b.y; mzi[k] = b.z;
        accA[k] = 0.0f; accB[k] = 0.0f;
    }

    if (!predFlag) {
        JLOOP(false)
    } else {
        JLOOP(true)
    }

    float sA = 0.0f, sB = 0.0f;
#pragma unroll
    for (int k = 0; k < IR; k++) { sA += accA[k]; sB += accB[k]; }
    float ps = (sA + W2F * sB) * coeff;

    for (int off = 32; off > 0; off >>= 1) ps += __shfl_down(ps, off, 64);

    __shared__ float wsum[BLOCK / 64];
    int wid = tid >> 6;
    int lane = tid & 63;
    if (lane == 0) wsum[wid] = ps;
    __syncthreads();
    if (tid == 0) {
        float bs = 0.0f;
        for (int w = 0; w < BLOCK / 64; w++) bs += wsum[w];
        atomicAdd(out, bs);
    }
}

extern "C" void kernel_launch(void* const* d_in, const int* in_sizes, int n_in,
                              void* d_out, int out_size, void* d_ws, size_t ws_size,
                              hipStream_t stream) {
    const float* vpred = (const float*)d_in[0];
    const float* vtarg = (const float*)d_in[1];
    const int* pf = (const int*)d_in[2];
    const int* tf = (const int*)d_in[3];
    float* out = (float*)d_out;
    float4* ws4 = (float4*)d_ws;

    int F = in_sizes[2] / 3;  // B == 1

    hipMemsetAsync(out, 0, sizeof(float), stream);

    int gthreads = 2 * F;
    geom_kernel<<<(gthreads + BLOCK - 1) / BLOCK, BLOCK, 0, stream>>>(
        vpred, vtarg, pf, tf, ws4, out, F);

    int iPerBlk = BLOCK * IR;
    int nIB = (F + iPerBlk - 1) / iPerBlk;
    int nJC = (F + JCHUNK - 1) / JCHUNK;
    int q = iPerBlk / JCHUNK;
    int nSym = 0;
    for (int ib = 0; ib < nIB; ++ib) {
        int c = (ib + 1) * q;
        if (c > nJC) c = nJC;
        nSym += c;
    }
    int blocks = 2 * nSym + nIB * nJC;
    pair_kernel<<<blocks, BLOCK, 0, stream>>>(ws4, out, F, nJC, nSym);
}